// Round 13
// baseline (179.222 us; speedup 1.0000x reference)
//
#include <hip/hip_runtime.h>

#define DIN   128
#define DSL   64
#define KSL   11
#define NTOK  4096
#define NB    64
#define LN_EPS   1e-5f
#define ATTN_EPS 1e-8f
#define SCALE    0.125f      // 64^-0.5

typedef __bf16 bf16x8 __attribute__((ext_vector_type(8)));
typedef float  f32x4  __attribute__((ext_vector_type(4)));
typedef unsigned int u32x4 __attribute__((ext_vector_type(4)));

static __device__ __forceinline__ bf16x8 ntload8(const __bf16* p) {
  union { u32x4 u; bf16x8 v; } c;
  c.u = __builtin_nontemporal_load((const u32x4*)p);
  return c.v;
}

// ---------------------------------------------------------------------------
// Kernel 0 (73 blocks x 704): blocks 0..7 gather W' = diag(g)·[Wk|Wv] into
// MFMA A-frag order; block 8: EP (G, Bt); blocks 9..72: slots broadcast +
// q = SCALE·(LN_q(slots) @ Wq) for batch b = blockIdx-9.
// ---------------------------------------------------------------------------
__launch_bounds__(704)
__global__ void k_prepinit(const float* __restrict__ Wk, const float* __restrict__ Wv,
                           const float* __restrict__ g, const float* __restrict__ b,
                           __bf16* __restrict__ WTf, float* __restrict__ EP,
                           const float* __restrict__ init_lat, const float* __restrict__ qg,
                           const float* __restrict__ qb, const float* __restrict__ Wq,
                           float* __restrict__ slots, float* __restrict__ q) {
  const int blk = blockIdx.x, tid = threadIdx.x;
  if (blk < 8) {
    if (tid < 256) {
      const int t = blk * 256 + tid;
      const int fid = t >> 6, lane = t & 63;
      const int ks = fid >> 3, nt = fid & 7;
      const int col = nt * 16 + (lane & 15);
      const int kb  = ks * 32 + (lane >> 4) * 8;
      union { uint4 u; __bf16 h[8]; } o;
#pragma unroll
      for (int j = 0; j < 8; ++j) {
        const int k = kb + j;
        const float v = ((col < 64) ? Wk[k * 64 + col] : Wv[k * 64 + (col - 64)]) * g[k];
        o.h[j] = (__bf16)v;
      }
      *((uint4*)WTf + t) = o.u;
    }
    return;
  }
  if (blk == 8) {
    if (tid < 128) {
      const float* __restrict__ W = (tid < 64) ? Wk : Wv;
      const int cc = tid & 63;
      float G = 0.f, Bt = 0.f;
      for (int k = 0; k < 128; ++k) {
        const float w = W[k * 64 + cc];
        G += g[k] * w; Bt += b[k] * w;
      }
      EP[tid] = G; EP[128 + tid] = Bt;
    }
    return;
  }
  const int bb = blk - 9;
  const int k = tid >> 6, c = tid & 63;
  const float s = init_lat[k * DSL + c];
  slots[(size_t)(bb * KSL + k) * DSL + c] = s;
  float sum = s, sq = s * s;
#pragma unroll
  for (int o = 32; o > 0; o >>= 1) { sum += __shfl_xor(sum, o); sq += __shfl_xor(sq, o); }
  const float m = sum * (1.f / 64.f);
  const float rstd = rsqrtf(sq * (1.f / 64.f) - m * m + LN_EPS);
  const float qn = (s - m) * rstd * qg[c] + qb[c];
  float acc = 0.f;
  for (int i = 0; i < DSL; ++i) acc += __shfl(qn, i) * Wq[i * DSL + c];
  q[(size_t)(bb * KSL + k) * DSL + c] = acc * SCALE;
}

// ---------------------------------------------------------------------------
// Kernel 1: fused LN+projection (r5 body) + ATTENTION ITER 0.
// Epilogue also drops keys/vals into LDS tiles; after one barrier, wave 0
// runs QK->softmax->PV for the block's 64 tokens (split = blockIdx & 63,
// NSPLIT=64) and writes Upart/Spart. Deletes the first k_attn dispatch.
// ---------------------------------------------------------------------------
__launch_bounds__(256)
__global__ void k_lnproj(const float* __restrict__ inp, const __bf16* __restrict__ WTf,
                         const float* __restrict__ EP, const float* __restrict__ q,
                         __bf16* __restrict__ keys, __bf16* __restrict__ valsT,
                         float* __restrict__ Upart, float* __restrict__ Spart) {
  __shared__ __bf16 Xs[4][16][136];
  __shared__ float rowstats[4][16][2];
  __shared__ __bf16 Ks[64][72];
  __shared__ __bf16 Vs[64][72];
  __shared__ __bf16 P[16][72];
  const int tid = threadIdx.x, wave = tid >> 6, lane = tid & 63;
  const int half = lane >> 5, hl = lane & 31;
  const int t = lane & 15, g = lane >> 4;
  const int rbase = blockIdx.x * 64 + wave * 16;

  float4 xr[8];
#pragma unroll
  for (int p = 0; p < 8; ++p)
    xr[p] = *(const float4*)(inp + (size_t)(rbase + 2 * p + half) * DIN + hl * 4);

  float s[8], sq[8];
#pragma unroll
  for (int p = 0; p < 8; ++p) {
    s[p]  = xr[p].x + xr[p].y + xr[p].z + xr[p].w;
    sq[p] = xr[p].x * xr[p].x + xr[p].y * xr[p].y + xr[p].z * xr[p].z + xr[p].w * xr[p].w;
    union { ushort4 u; __bf16 h[4]; } pk;
    pk.h[0] = (__bf16)xr[p].x; pk.h[1] = (__bf16)xr[p].y;
    pk.h[2] = (__bf16)xr[p].z; pk.h[3] = (__bf16)xr[p].w;
    *(ushort4*)&Xs[wave][2 * p + half][hl * 4] = pk.u;
  }
#pragma unroll
  for (int o = 16; o > 0; o >>= 1) {
#pragma unroll
    for (int p = 0; p < 8; ++p) { s[p] += __shfl_xor(s[p], o); sq[p] += __shfl_xor(sq[p], o); }
  }
  if (hl < 8) {
    const int p = hl;
    const float m = s[p] * (1.f / 128.f);
    const float rstd = rsqrtf(sq[p] * (1.f / 128.f) - m * m + LN_EPS);
    rowstats[wave][2 * p + half][0] = m;
    rowstats[wave][2 * p + half][1] = rstd;
  }
  const bf16x8* __restrict__ Wv8 = (const bf16x8*)WTf;
  f32x4 acc[8] = {};
#pragma unroll
  for (int ks = 0; ks < 4; ++ks) {
    const bf16x8 xf = *(const bf16x8*)&Xs[wave][t][ks * 32 + g * 8];
#pragma unroll
    for (int nt = 0; nt < 8; ++nt) {
      const bf16x8 wf = Wv8[(ks * 8 + nt) * 64 + lane];
      acc[nt] = __builtin_amdgcn_mfma_f32_16x16x32_bf16(wf, xf, acc[nt], 0, 0, 0);
    }
  }
  const float2 mrs = *(const float2*)&rowstats[wave][t][0];
  const float rstd = mrs.y, mm = mrs.x * mrs.y;
  const int bidx = rbase >> 12;
  const int tIB  = (rbase & 4095) + t;
  const int ltok = wave * 16 + t;                 // token within block (0..63)
#pragma unroll
  for (int nt = 0; nt < 8; ++nt) {
    const float4 Gv = *(const float4*)(EP + nt * 16 + g * 4);
    const float4 Bv = *(const float4*)(EP + 128 + nt * 16 + g * 4);
    const float o0 = rstd * acc[nt][0] - mm * Gv.x + Bv.x;
    const float o1 = rstd * acc[nt][1] - mm * Gv.y + Bv.y;
    const float o2 = rstd * acc[nt][2] - mm * Gv.z + Bv.z;
    const float o3 = rstd * acc[nt][3] - mm * Gv.w + Bv.w;
    if (nt < 4) {
      union { unsigned long long u; __bf16 h[4]; } pk;
      pk.h[0] = (__bf16)o0; pk.h[1] = (__bf16)o1; pk.h[2] = (__bf16)o2; pk.h[3] = (__bf16)o3;
      *(unsigned long long*)&keys[(size_t)(rbase + t) * 64 + nt * 16 + g * 4] = pk.u;
      *(unsigned long long*)&Ks[ltok][nt * 16 + g * 4] = pk.u;
    } else {
      const int vc = (nt - 4) * 16 + g * 4;
      const __bf16 h0 = (__bf16)o0, h1 = (__bf16)o1, h2 = (__bf16)o2, h3 = (__bf16)o3;
      valsT[((size_t)bidx * 64 + vc + 0) * NTOK + tIB] = h0;
      valsT[((size_t)bidx * 64 + vc + 1) * NTOK + tIB] = h1;
      valsT[((size_t)bidx * 64 + vc + 2) * NTOK + tIB] = h2;
      valsT[((size_t)bidx * 64 + vc + 3) * NTOK + tIB] = h3;
      Vs[vc + 0][ltok] = h0;
      Vs[vc + 1][ltok] = h1;
      Vs[vc + 2][ltok] = h2;
      Vs[vc + 3][ltok] = h3;
    }
  }
  __syncthreads();
  if (wave != 0) return;

  // ---- fused attention iter 0 for this block's 64 tokens ----
  const int b = blockIdx.x >> 6, sp = blockIdx.x & 63;
  bf16x8 qf[2];
#pragma unroll
  for (int ks = 0; ks < 2; ++ks) {
    float4 q0 = {0.f, 0.f, 0.f, 0.f}, q1 = {0.f, 0.f, 0.f, 0.f};
    if (t < KSL) {
      const float* __restrict__ qp = q + (size_t)(b * KSL + t) * DSL + ks * 32 + g * 8;
      q0 = *(const float4*)qp; q1 = *(const float4*)(qp + 4);
    }
    qf[ks][0] = (__bf16)q0.x; qf[ks][1] = (__bf16)q0.y;
    qf[ks][2] = (__bf16)q0.z; qf[ks][3] = (__bf16)q0.w;
    qf[ks][4] = (__bf16)q1.x; qf[ks][5] = (__bf16)q1.y;
    qf[ks][6] = (__bf16)q1.z; qf[ks][7] = (__bf16)q1.w;
  }
  f32x4 c[4] = {};
#pragma unroll
  for (int ks = 0; ks < 2; ++ks)
#pragma unroll
    for (int tile = 0; tile < 4; ++tile) {
      const bf16x8 kf = *(const bf16x8*)&Ks[tile * 16 + t][ks * 32 + g * 8];
      c[tile] = __builtin_amdgcn_mfma_f32_16x16x32_bf16(qf[ks], kf, c[tile], 0, 0, 0);
    }
  float lg[4][4], mx[4];
#pragma unroll
  for (int tile = 0; tile < 4; ++tile) {
#pragma unroll
    for (int r = 0; r < 4; ++r)
      lg[tile][r] = (4 * g + r < KSL) ? c[tile][r] : -1e30f;   // q pre-scaled
    mx[tile] = fmaxf(fmaxf(lg[tile][0], lg[tile][1]), fmaxf(lg[tile][2], lg[tile][3]));
  }
#pragma unroll
  for (int tile = 0; tile < 4; ++tile) mx[tile] = fmaxf(mx[tile], __shfl_xor(mx[tile], 16));
#pragma unroll
  for (int tile = 0; tile < 4; ++tile) mx[tile] = fmaxf(mx[tile], __shfl_xor(mx[tile], 32));
  float se[4];
#pragma unroll
  for (int tile = 0; tile < 4; ++tile) {
#pragma unroll
    for (int r = 0; r < 4; ++r) lg[tile][r] = __expf(lg[tile][r] - mx[tile]);
    se[tile] = lg[tile][0] + lg[tile][1] + lg[tile][2] + lg[tile][3];
  }
#pragma unroll
  for (int tile = 0; tile < 4; ++tile) se[tile] += __shfl_xor(se[tile], 16);
#pragma unroll
  for (int tile = 0; tile < 4; ++tile) se[tile] += __shfl_xor(se[tile], 32);
  float sacc[4] = {0.f, 0.f, 0.f, 0.f};
#pragma unroll
  for (int tile = 0; tile < 4; ++tile) {
    const float inv = 1.f / se[tile];
#pragma unroll
    for (int r = 0; r < 4; ++r) {
      const float a = lg[tile][r] * inv + ATTN_EPS;
      sacc[r] += a;
      P[4 * g + r][tile * 16 + t] = (__bf16)a;
    }
  }
  f32x4 U[4] = {};
#pragma unroll
  for (int ks = 0; ks < 2; ++ks) {
    const bf16x8 pf = *(const bf16x8*)&P[t][ks * 32 + g * 8];
#pragma unroll
    for (int ct = 0; ct < 4; ++ct) {
      const bf16x8 vf = *(const bf16x8*)&Vs[ct * 16 + t][ks * 32 + g * 8];
      U[ct] = __builtin_amdgcn_mfma_f32_16x16x32_bf16(pf, vf, U[ct], 0, 0, 0);
    }
  }
  float* __restrict__ up = Upart + (size_t)(b * 64 + sp) * (KSL * DSL);
#pragma unroll
  for (int ct = 0; ct < 4; ++ct)
#pragma unroll
    for (int r = 0; r < 4; ++r)
      if (4 * g + r < KSL) up[(4 * g + r) * DSL + ct * 16 + t] = U[ct][r];
#pragma unroll
  for (int r = 0; r < 4; ++r) {
#pragma unroll
    for (int o = 1; o < 16; o <<= 1) sacc[r] += __shfl_xor(sacc[r], o);
  }
  if (t == 0) {
    float* __restrict__ spp = Spart + (size_t)(b * 64 + sp) * 16;
#pragma unroll
    for (int r = 0; r < 4; ++r) spp[4 * g + r] = sacc[r];
  }
}

// ---------------------------------------------------------------------------
// Kernel 3: attention via MFMA, batched softmax. 1 wave / 128 tokens.
// NSPLIT=32. LAST: nt loads + attn_out nt writes.
// ---------------------------------------------------------------------------
template <bool LAST>
__launch_bounds__(64)
__global__ void k_attn(const __bf16* __restrict__ keys, const __bf16* __restrict__ valsT,
                       const float* __restrict__ q, float* __restrict__ Upart,
                       float* __restrict__ Spart, float* __restrict__ attn_out) {
  __shared__ __bf16 P[2][16][72];
  const int b = blockIdx.x >> 5, sp = blockIdx.x & 31;
  const int lane = threadIdx.x;
  const int g = lane >> 4, t = lane & 15;

  bf16x8 qf[2];
#pragma unroll
  for (int ks = 0; ks < 2; ++ks) {
    float4 q0 = {0.f, 0.f, 0.f, 0.f}, q1 = {0.f, 0.f, 0.f, 0.f};
    if (t < KSL) {
      const float* __restrict__ qp = q + (size_t)(b * KSL + t) * DSL + ks * 32 + g * 8;
      q0 = *(const float4*)qp; q1 = *(const float4*)(qp + 4);
    }
    qf[ks][0] = (__bf16)q0.x; qf[ks][1] = (__bf16)q0.y;
    qf[ks][2] = (__bf16)q0.z; qf[ks][3] = (__bf16)q0.w;
    qf[ks][4] = (__bf16)q1.x; qf[ks][5] = (__bf16)q1.y;
    qf[ks][6] = (__bf16)q1.z; qf[ks][7] = (__bf16)q1.w;
  }

  const __bf16* __restrict__ kbase = keys + ((size_t)b * NTOK + sp * 128) * DSL;
  const __bf16* __restrict__ vbase = valsT + (size_t)b * DSL * NTOK + sp * 128;
  float sacc[4] = {0.f, 0.f, 0.f, 0.f};
  f32x4 U[4] = {};

#pragma unroll
  for (int gr = 0; gr < 2; ++gr) {
    const int tb = gr * 64;
    bf16x8 kf[4][2];
#pragma unroll
    for (int tile = 0; tile < 4; ++tile)
#pragma unroll
      for (int ks = 0; ks < 2; ++ks) {
        const __bf16* ap = kbase + (size_t)(tb + tile * 16 + t) * DSL + ks * 32 + g * 8;
        kf[tile][ks] = LAST ? ntload8(ap) : *(const bf16x8*)ap;
      }
    bf16x8 vf[2][4];
#pragma unroll
    for (int ks = 0; ks < 2; ++ks)
#pragma unroll
      for (int ct = 0; ct < 4; ++ct) {
        const __bf16* ap = vbase + (size_t)(ct * 16 + t) * NTOK + tb + ks * 32 + g * 8;
        vf[ks][ct] = LAST ? ntload8(ap) : *(const bf16x8*)ap;
      }
    f32x4 c[4] = {};
#pragma unroll
    for (int ks = 0; ks < 2; ++ks)
#pragma unroll
      for (int tile = 0; tile < 4; ++tile)
        c[tile] = __builtin_amdgcn_mfma_f32_16x16x32_bf16(qf[ks], kf[tile][ks], c[tile], 0, 0, 0);
    float lg[4][4], mx[4];
#pragma unroll
    for (int tile = 0; tile < 4; ++tile) {
#pragma unroll
      for (int r = 0; r < 4; ++r)
        lg[tile][r] = (4 * g + r < KSL) ? c[tile][r] : -1e30f;   // q pre-scaled
      mx[tile] = fmaxf(fmaxf(lg[tile][0], lg[tile][1]), fmaxf(lg[tile][2], lg[tile][3]));
    }
#pragma unroll
    for (int tile = 0; tile < 4; ++tile) mx[tile] = fmaxf(mx[tile], __shfl_xor(mx[tile], 16));
#pragma unroll
    for (int tile = 0; tile < 4; ++tile) mx[tile] = fmaxf(mx[tile], __shfl_xor(mx[tile], 32));
    float se[4];
#pragma unroll
    for (int tile = 0; tile < 4; ++tile) {
#pragma unroll
      for (int r = 0; r < 4; ++r) lg[tile][r] = __expf(lg[tile][r] - mx[tile]);
      se[tile] = lg[tile][0] + lg[tile][1] + lg[tile][2] + lg[tile][3];
    }
#pragma unroll
    for (int tile = 0; tile < 4; ++tile) se[tile] += __shfl_xor(se[tile], 16);
#pragma unroll
    for (int tile = 0; tile < 4; ++tile) se[tile] += __shfl_xor(se[tile], 32);
#pragma unroll
    for (int tile = 0; tile < 4; ++tile) {
      const float inv = 1.f / se[tile];
#pragma unroll
      for (int r = 0; r < 4; ++r) {
        const float a = lg[tile][r] * inv + ATTN_EPS;
        sacc[r] += a;
        P[gr][4 * g + r][tile * 16 + t] = (__bf16)a;
        if constexpr (LAST) {
          if (4 * g + r < KSL)
            __builtin_nontemporal_store(
                a, &attn_out[((size_t)b * NTOK + sp * 128 + tb + tile * 16 + t) * KSL + 4 * g + r]);
        }
      }
    }
#pragma unroll
    for (int ks = 0; ks < 2; ++ks) {
      const bf16x8 pf = *(const bf16x8*)&P[gr][t][ks * 32 + g * 8];
#pragma unroll
      for (int ct = 0; ct < 4; ++ct)
        U[ct] = __builtin_amdgcn_mfma_f32_16x16x32_bf16(pf, vf[ks][ct], U[ct], 0, 0, 0);
    }
  }

  float* __restrict__ up = Upart + (size_t)(b * 32 + sp) * (KSL * DSL);
#pragma unroll
  for (int ct = 0; ct < 4; ++ct)
#pragma unroll
    for (int r = 0; r < 4; ++r)
      if (4 * g + r < KSL) up[(4 * g + r) * DSL + ct * 16 + t] = U[ct][r];

#pragma unroll
  for (int r = 0; r < 4; ++r) {
#pragma unroll
    for (int o = 1; o < 16; o <<= 1) sacc[r] += __shfl_xor(sacc[r], o);
  }
  if (t == 0) {
    float* __restrict__ spp = Spart + (size_t)(b * 32 + sp) * 16;
#pragma unroll
    for (int r = 0; r < 4; ++r) spp[4 * g + r] = sacc[r];
  }
}

// ---------------------------------------------------------------------------
// Kernel 4: reduce -> GRU -> LN_f + MLP residual -> next q. 2 waves/row.
// NS = split count of the feeding attn pass (64 for iter 0, 32 after).
// ---------------------------------------------------------------------------
template <int NS, bool LAST>
__launch_bounds__(128)
__global__ void k_update(const float* __restrict__ Upart, const float* __restrict__ Spart,
                         float* __restrict__ slots, const float* __restrict__ w_ih,
                         const float* __restrict__ w_hh, const float* __restrict__ b_ih,
                         const float* __restrict__ b_hh, const float* __restrict__ fg,
                         const float* __restrict__ fb, const float* __restrict__ W1,
                         const float* __restrict__ b1v, const float* __restrict__ W2,
                         const float* __restrict__ b2v, const float* __restrict__ qg,
                         const float* __restrict__ qbv, const float* __restrict__ Wq,
                         float* __restrict__ q, float* __restrict__ out_slots) {
  __shared__ float rU[2][64];
  __shared__ float rS[2];
  __shared__ float rG[2][6][64];
  __shared__ float rH[2][4][64];
  __shared__ float rO[2][64];
  __shared__ float rQ[2][64];
  const int w = threadIdx.x >> 6, c = threadIdx.x & 63;
  const int row = blockIdx.x;            // 0..703
  const int b = row / 11, k = row - b * 11;

  float upi = 0.f, ssp = 0.f;
  for (int s = w * (NS / 2); s < (w + 1) * (NS / 2); ++s) {
    upi += __builtin_nontemporal_load(&Upart[((size_t)(b * NS + s) * KSL + k) * DSL + c]);
    ssp += __builtin_nontemporal_load(&Spart[(size_t)(b * NS + s) * 16 + k]);
  }
  rU[w][c] = upi;
  if (c == 0) rS[w] = ssp;
  const float h = slots[(size_t)row * DSL + c];
  __syncthreads();
  const float u = (rU[0][c] + rU[1][c]) / (rS[0] + rS[1]);

  float gr = 0.f, gz = 0.f, gn = 0.f, hr = 0.f, hz = 0.f, hn = 0.f;
  for (int i = w * 32; i < w * 32 + 32; ++i) {
    const float ui = __shfl(u, i), hi = __shfl(h, i);
    gr += ui * w_ih[i * 192 + c];       hr += hi * w_hh[i * 192 + c];
    gz += ui * w_ih[i * 192 + 64 + c];  hz += hi * w_hh[i * 192 + 64 + c];
    gn += ui * w_ih[i * 192 + 128 + c]; hn += hi * w_hh[i * 192 + 128 + c];
  }
  rG[w][0][c] = gr; rG[w][1][c] = gz; rG[w][2][c] = gn;
  rG[w][3][c] = hr; rG[w][4][c] = hz; rG[w][5][c] = hn;
  __syncthreads();
  gr = rG[0][0][c] + rG[1][0][c] + b_ih[c];
  gz = rG[0][1][c] + rG[1][1][c] + b_ih[64 + c];
  gn = rG[0][2][c] + rG[1][2][c] + b_ih[128 + c];
  hr = rG[0][3][c] + rG[1][3][c] + b_hh[c];
  hz = rG[0][4][c] + rG[1][4][c] + b_hh[64 + c];
  hn = rG[0][5][c] + rG[1][5][c] + b_hh[128 + c];
  const float r = 1.f / (1.f + __expf(-(gr + hr)));
  const float z = 1.f / (1.f + __expf(-(gz + hz)));
  const float nn = tanhf(gn + r * hn);
  float sv = (1.f - z) * nn + z * h;

  float sum = sv, sq = sv * sv;
#pragma unroll
  for (int o = 32; o > 0; o >>= 1) { sum += __shfl_xor(sum, o); sq += __shfl_xor(sq, o); }
  float m = sum * (1.f / 64.f);
  float rstd = rsqrtf(sq * (1.f / 64.f) - m * m + LN_EPS);
  const float sl = (sv - m) * rstd * fg[c] + fb[c];

  float h0 = 0.f, h1 = 0.f, h2 = 0.f, h3 = 0.f;
  for (int i = w * 32; i < w * 32 + 32; ++i) {
    const float si = __shfl(sl, i);
    h0 += si * W1[i * 256 + c];        h1 += si * W1[i * 256 + 64 + c];
    h2 += si * W1[i * 256 + 128 + c];  h3 += si * W1[i * 256 + 192 + c];
  }
  rH[w][0][c] = h0; rH[w][1][c] = h1; rH[w][2][c] = h2; rH[w][3][c] = h3;
  __syncthreads();
  h0 = fmaxf(rH[0][0][c] + rH[1][0][c] + b1v[c], 0.f);
  h1 = fmaxf(rH[0][1][c] + rH[1][1][c] + b1v[64 + c], 0.f);
  h2 = fmaxf(rH[0][2][c] + rH[1][2][c] + b1v[128 + c], 0.f);
  h3 = fmaxf(rH[0][3][c] + rH[1][3][c] + b1v[192 + c], 0.f);

  float o = 0.f;
  {
    const float ha = (w == 0) ? h0 : h2;
    const float hb = (w == 0) ? h1 : h3;
    const int base = w * 128;
    for (int j = 0; j < 64; ++j) o += __shfl(ha, j) * W2[(base + j) * DSL + c];
    for (int j = 0; j < 64; ++j) o += __shfl(hb, j) * W2[(base + 64 + j) * DSL + c];
  }
  rO[w][c] = o;
  __syncthreads();
  sv += rO[0][c] + rO[1][c] + b2v[c];

  if constexpr (LAST) {
    if (w == 0)
      __builtin_nontemporal_store(sv, &out_slots[(size_t)row * DSL + c]);
  } else {
    float s2 = sv, q2 = sv * sv;
#pragma unroll
    for (int o2 = 32; o2 > 0; o2 >>= 1) { s2 += __shfl_xor(s2, o2); q2 += __shfl_xor(q2, o2); }
    m = s2 * (1.f / 64.f);
    rstd = rsqrtf(q2 * (1.f / 64.f) - m * m + LN_EPS);
    const float qn = (sv - m) * rstd * qg[c] + qbv[c];
    float qa = 0.f;
    for (int i = w * 32; i < w * 32 + 32; ++i) qa += __shfl(qn, i) * Wq[i * DSL + c];
    rQ[w][c] = qa;
    __syncthreads();
    if (w == 0) {
      slots[(size_t)row * DSL + c] = sv;
      q[(size_t)row * DSL + c] = (rQ[0][c] + rQ[1][c]) * SCALE;
    }
  }
}

// ---------------------------------------------------------------------------
extern "C" void kernel_launch(void* const* d_in, const int* in_sizes, int n_in,
                              void* d_out, int out_size, void* d_ws, size_t ws_size,
                              hipStream_t stream) {
  const float* inp  = (const float*)d_in[0];
  const float* lng  = (const float*)d_in[1];
  const float* lnb  = (const float*)d_in[2];
  const float* Wk   = (const float*)d_in[3];
  const float* Wv   = (const float*)d_in[4];
  const float* init = (const float*)d_in[5];
  const float* qg   = (const float*)d_in[6];
  const float* qbb  = (const float*)d_in[7];
  const float* Wq   = (const float*)d_in[8];
  const float* wih  = (const float*)d_in[9];
  const float* whh  = (const float*)d_in[10];
  const float* bih  = (const float*)d_in[11];
  const float* bhh  = (const float*)d_in[12];
  const float* fg   = (const float*)d_in[13];
  const float* fb   = (const float*)d_in[14];
  const float* W1   = (const float*)d_in[15];
  const float* b1   = (const float*)d_in[16];
  const float* W2   = (const float*)d_in[17];
  const float* b2   = (const float*)d_in[18];

  char* wsb = (char*)d_ws;
  __bf16* keys  = (__bf16*)wsb;                                  // 33.55 MB
  __bf16* valsT = keys + (size_t)NB * NTOK * DSL;                // 33.55 MB
  __bf16* WTf   = valsT + (size_t)NB * DSL * NTOK;               // 32 KB
  float*  EP    = (float*)(WTf + 16384);                         // 1 KB
  float* slots = EP + 256;
  float* q     = slots + NB * KSL * DSL;
  float* Upart = q + NB * KSL * DSL;                             // 11.5 MB (64 splits)
  float* Spart = Upart + (size_t)NB * 64 * KSL * DSL;            // 256 KB

  float* out_slots = (float*)d_out;
  float* out_attn  = (float*)d_out + NB * KSL * DSL;

  k_prepinit<<<73, 704, 0, stream>>>(Wk, Wv, lng, lnb, WTf, EP,
                                     init, qg, qbb, Wq, slots, q);
  // lnproj + fused attention iter 0 (NSPLIT=64)
  k_lnproj<<<4096, 256, 0, stream>>>(inp, WTf, EP, q, keys, valsT, Upart, Spart);
  k_update<64, false><<<NB * KSL, 128, 0, stream>>>(Upart, Spart, slots, wih, whh, bih, bhh,
                                                    fg, fb, W1, b1, W2, b2, qg, qbb, Wq, q,
                                                    nullptr);
  // iter 1
  k_attn<false><<<NB * 32, 64, 0, stream>>>(keys, valsT, q, Upart, Spart, nullptr);
  k_update<32, false><<<NB * KSL, 128, 0, stream>>>(Upart, Spart, slots, wih, whh, bih, bhh,
                                                    fg, fb, W1, b1, W2, b2, qg, qbb, Wq, q,
                                                    nullptr);
  // iter 2
  k_attn<true><<<NB * 32, 64, 0, stream>>>(keys, valsT, q, Upart, Spart, out_attn);
  k_update<32, true><<<NB * KSL, 128, 0, stream>>>(Upart, Spart, slots, wih, whh, bih, bhh,
                                                   fg, fb, W1, b1, W2, b2, qg, qbb, Wq, q,
                                                   out_slots);
}

// Round 14
// 153.239 us; speedup vs baseline: 1.1696x; 1.1696x over previous
//
#include <hip/hip_runtime.h>

#define DIN   128
#define DSL   64
#define KSL   11
#define NTOK  4096
#define NB    64
#define NSPLIT 32
#define LN_EPS   1e-5f
#define ATTN_EPS 1e-8f
#define SCALE    0.125f      // 64^-0.5

typedef __bf16 bf16x8 __attribute__((ext_vector_type(8)));
typedef float  f32x4  __attribute__((ext_vector_type(4)));
typedef unsigned int u32x4 __attribute__((ext_vector_type(4)));

static __device__ __forceinline__ bf16x8 ntload8(const __bf16* p) {
  union { u32x4 u; bf16x8 v; } c;
  c.u = __builtin_nontemporal_load((const u32x4*)p);
  return c.v;
}

#define AS1 __attribute__((address_space(1)))
#define AS3 __attribute__((address_space(3)))
static __device__ __forceinline__ void gload_lds16(const void* g, void* l) {
  // async global->LDS, 16B per lane: LDS dest = base + lane*16 (linear)
  __builtin_amdgcn_global_load_lds((const AS1 unsigned int*)g, (AS3 unsigned int*)l,
                                   16, 0, 0);
}

// ---------------------------------------------------------------------------
// Kernel 0 (73 blocks x 704): blocks 0..7 gather W' = diag(g)·[Wk|Wv] into
// MFMA A-frag order; block 8: EP (G, Bt); blocks 9..72: slots broadcast +
// q = SCALE·(LN_q(slots) @ Wq) for batch b = blockIdx-9.
// ---------------------------------------------------------------------------
__launch_bounds__(704)
__global__ void k_prepinit(const float* __restrict__ Wk, const float* __restrict__ Wv,
                           const float* __restrict__ g, const float* __restrict__ b,
                           __bf16* __restrict__ WTf, float* __restrict__ EP,
                           const float* __restrict__ init_lat, const float* __restrict__ qg,
                           const float* __restrict__ qb, const float* __restrict__ Wq,
                           float* __restrict__ slots, float* __restrict__ q) {
  const int blk = blockIdx.x, tid = threadIdx.x;
  if (blk < 8) {
    if (tid < 256) {
      const int t = blk * 256 + tid;
      const int fid = t >> 6, lane = t & 63;
      const int ks = fid >> 3, nt = fid & 7;
      const int col = nt * 16 + (lane & 15);
      const int kb  = ks * 32 + (lane >> 4) * 8;
      union { uint4 u; __bf16 h[8]; } o;
#pragma unroll
      for (int j = 0; j < 8; ++j) {
        const int k = kb + j;
        const float v = ((col < 64) ? Wk[k * 64 + col] : Wv[k * 64 + (col - 64)]) * g[k];
        o.h[j] = (__bf16)v;
      }
      *((uint4*)WTf + t) = o.u;
    }
    return;
  }
  if (blk == 8) {
    if (tid < 128) {
      const float* __restrict__ W = (tid < 64) ? Wk : Wv;
      const int cc = tid & 63;
      float G = 0.f, Bt = 0.f;
      for (int k = 0; k < 128; ++k) {
        const float w = W[k * 64 + cc];
        G += g[k] * w; Bt += b[k] * w;
      }
      EP[tid] = G; EP[128 + tid] = Bt;
    }
    return;
  }
  const int bb = blk - 9;
  const int k = tid >> 6, c = tid & 63;
  const float s = init_lat[k * DSL + c];
  slots[(size_t)(bb * KSL + k) * DSL + c] = s;
  float sum = s, sq = s * s;
#pragma unroll
  for (int o = 32; o > 0; o >>= 1) { sum += __shfl_xor(sum, o); sq += __shfl_xor(sq, o); }
  const float m = sum * (1.f / 64.f);
  const float rstd = rsqrtf(sq * (1.f / 64.f) - m * m + LN_EPS);
  const float qn = (s - m) * rstd * qg[c] + qb[c];
  float acc = 0.f;
  for (int i = 0; i < DSL; ++i) acc += __shfl(qn, i) * Wq[i * DSL + c];
  q[(size_t)(bb * KSL + k) * DSL + c] = acc * SCALE;
}

// ---------------------------------------------------------------------------
// Kernel 1: fused LN+projection. NEW: input staged via async global_load_lds
// (width 16, linear 1KB chunks; wave w stages its own 16 rows), then the
// proven r5 body reads rows from LDS. LN folded into epilogue.
// ---------------------------------------------------------------------------
__launch_bounds__(256)
__global__ void k_lnproj(const float* __restrict__ inp, const __bf16* __restrict__ WTf,
                         const float* __restrict__ EP, __bf16* __restrict__ keys,
                         __bf16* __restrict__ valsT) {
  __shared__ float Xf[64 * 128];         // 32 KB staged f32 tile (linear)
  __shared__ __bf16 Xs[4][16][136];      // 17.4 KB bf16 fragments (padded)
  __shared__ float rowstats[4][16][2];
  const int tid = threadIdx.x, wave = tid >> 6, lane = tid & 63;
  const int half = lane >> 5, hl = lane & 31;
  const int t = lane & 15, g = lane >> 4;
  const int rbase = blockIdx.x * 64 + wave * 16;

  // ---- async stage: 8 chunks x 1KB per wave (covers this wave's 16 rows) ----
  {
    const float* __restrict__ gbase = inp + (size_t)blockIdx.x * 64 * DIN;
#pragma unroll
    for (int j = 0; j < 8; ++j) {
      const int c = wave * 8 + j;        // chunk = 2 rows (1 KB)
      gload_lds16(gbase + c * 256 + lane * 4, &Xf[c * 256]);
    }
  }
  __syncthreads();   // drains vmcnt (global_load_lds) for all waves

  // ---- stats + bf16 pack from LDS (r5 pattern) ----
  float4 xr[8];
#pragma unroll
  for (int p = 0; p < 8; ++p)
    xr[p] = *(const float4*)&Xf[(wave * 16 + 2 * p + half) * DIN + hl * 4];

  float s[8], sq[8];
#pragma unroll
  for (int p = 0; p < 8; ++p) {
    s[p]  = xr[p].x + xr[p].y + xr[p].z + xr[p].w;
    sq[p] = xr[p].x * xr[p].x + xr[p].y * xr[p].y + xr[p].z * xr[p].z + xr[p].w * xr[p].w;
    union { ushort4 u; __bf16 h[4]; } pk;
    pk.h[0] = (__bf16)xr[p].x; pk.h[1] = (__bf16)xr[p].y;
    pk.h[2] = (__bf16)xr[p].z; pk.h[3] = (__bf16)xr[p].w;
    *(ushort4*)&Xs[wave][2 * p + half][hl * 4] = pk.u;
  }
#pragma unroll
  for (int o = 16; o > 0; o >>= 1) {
#pragma unroll
    for (int p = 0; p < 8; ++p) { s[p] += __shfl_xor(s[p], o); sq[p] += __shfl_xor(sq[p], o); }
  }
  if (hl < 8) {
    const int p = hl;
    const float m = s[p] * (1.f / 128.f);
    const float rstd = rsqrtf(sq[p] * (1.f / 128.f) - m * m + LN_EPS);
    rowstats[wave][2 * p + half][0] = m;
    rowstats[wave][2 * p + half][1] = rstd;
  }
  const bf16x8* __restrict__ Wv8 = (const bf16x8*)WTf;
  f32x4 acc[8] = {};
#pragma unroll
  for (int ks = 0; ks < 4; ++ks) {
    const bf16x8 xf = *(const bf16x8*)&Xs[wave][t][ks * 32 + g * 8];
#pragma unroll
    for (int nt = 0; nt < 8; ++nt) {
      const bf16x8 wf = Wv8[(ks * 8 + nt) * 64 + lane];
      acc[nt] = __builtin_amdgcn_mfma_f32_16x16x32_bf16(wf, xf, acc[nt], 0, 0, 0);
    }
  }
  const float2 mrs = *(const float2*)&rowstats[wave][t][0];
  const float rstd = mrs.y, mm = mrs.x * mrs.y;
  const int bidx = rbase >> 12;
  const int tIB  = (rbase & 4095) + t;
#pragma unroll
  for (int nt = 0; nt < 8; ++nt) {
    const float4 Gv = *(const float4*)(EP + nt * 16 + g * 4);
    const float4 Bv = *(const float4*)(EP + 128 + nt * 16 + g * 4);
    const float o0 = rstd * acc[nt][0] - mm * Gv.x + Bv.x;
    const float o1 = rstd * acc[nt][1] - mm * Gv.y + Bv.y;
    const float o2 = rstd * acc[nt][2] - mm * Gv.z + Bv.z;
    const float o3 = rstd * acc[nt][3] - mm * Gv.w + Bv.w;
    if (nt < 4) {
      union { unsigned long long u; __bf16 h[4]; } pk;
      pk.h[0] = (__bf16)o0; pk.h[1] = (__bf16)o1; pk.h[2] = (__bf16)o2; pk.h[3] = (__bf16)o3;
      *(unsigned long long*)&keys[(size_t)(rbase + t) * 64 + nt * 16 + g * 4] = pk.u;
    } else {
      const int vc = (nt - 4) * 16 + g * 4;
      valsT[((size_t)bidx * 64 + vc + 0) * NTOK + tIB] = (__bf16)o0;
      valsT[((size_t)bidx * 64 + vc + 1) * NTOK + tIB] = (__bf16)o1;
      valsT[((size_t)bidx * 64 + vc + 2) * NTOK + tIB] = (__bf16)o2;
      valsT[((size_t)bidx * 64 + vc + 3) * NTOK + tIB] = (__bf16)o3;
    }
  }
}

// ---------------------------------------------------------------------------
// Kernel 3: attention via MFMA, batched softmax. 1 wave / 128 tokens.
// LAST: nt loads for keys/valsT (dead after this pass) + attn_out nt writes.
// ---------------------------------------------------------------------------
template <bool LAST>
__launch_bounds__(64)
__global__ void k_attn(const __bf16* __restrict__ keys, const __bf16* __restrict__ valsT,
                       const float* __restrict__ q, float* __restrict__ Upart,
                       float* __restrict__ Spart, float* __restrict__ attn_out) {
  __shared__ __bf16 P[2][16][72];
  const int b = blockIdx.x >> 5, sp = blockIdx.x & 31;
  const int lane = threadIdx.x;
  const int g = lane >> 4, t = lane & 15;

  bf16x8 qf[2];
#pragma unroll
  for (int ks = 0; ks < 2; ++ks) {
    float4 q0 = {0.f, 0.f, 0.f, 0.f}, q1 = {0.f, 0.f, 0.f, 0.f};
    if (t < KSL) {
      const float* __restrict__ qp = q + (size_t)(b * KSL + t) * DSL + ks * 32 + g * 8;
      q0 = *(const float4*)qp; q1 = *(const float4*)(qp + 4);
    }
    qf[ks][0] = (__bf16)q0.x; qf[ks][1] = (__bf16)q0.y;
    qf[ks][2] = (__bf16)q0.z; qf[ks][3] = (__bf16)q0.w;
    qf[ks][4] = (__bf16)q1.x; qf[ks][5] = (__bf16)q1.y;
    qf[ks][6] = (__bf16)q1.z; qf[ks][7] = (__bf16)q1.w;
  }

  const __bf16* __restrict__ kbase = keys + ((size_t)b * NTOK + sp * 128) * DSL;
  const __bf16* __restrict__ vbase = valsT + (size_t)b * DSL * NTOK + sp * 128;
  float sacc[4] = {0.f, 0.f, 0.f, 0.f};
  f32x4 U[4] = {};

#pragma unroll
  for (int gr = 0; gr < 2; ++gr) {
    const int tb = gr * 64;
    bf16x8 kf[4][2];
#pragma unroll
    for (int tile = 0; tile < 4; ++tile)
#pragma unroll
      for (int ks = 0; ks < 2; ++ks) {
        const __bf16* ap = kbase + (size_t)(tb + tile * 16 + t) * DSL + ks * 32 + g * 8;
        kf[tile][ks] = LAST ? ntload8(ap) : *(const bf16x8*)ap;
      }
    bf16x8 vf[2][4];
#pragma unroll
    for (int ks = 0; ks < 2; ++ks)
#pragma unroll
      for (int ct = 0; ct < 4; ++ct) {
        const __bf16* ap = vbase + (size_t)(ct * 16 + t) * NTOK + tb + ks * 32 + g * 8;
        vf[ks][ct] = LAST ? ntload8(ap) : *(const bf16x8*)ap;
      }
    f32x4 c[4] = {};
#pragma unroll
    for (int ks = 0; ks < 2; ++ks)
#pragma unroll
      for (int tile = 0; tile < 4; ++tile)
        c[tile] = __builtin_amdgcn_mfma_f32_16x16x32_bf16(qf[ks], kf[tile][ks], c[tile], 0, 0, 0);
    float lg[4][4], mx[4];
#pragma unroll
    for (int tile = 0; tile < 4; ++tile) {
#pragma unroll
      for (int r = 0; r < 4; ++r)
        lg[tile][r] = (4 * g + r < KSL) ? c[tile][r] : -1e30f;   // q pre-scaled
      mx[tile] = fmaxf(fmaxf(lg[tile][0], lg[tile][1]), fmaxf(lg[tile][2], lg[tile][3]));
    }
#pragma unroll
    for (int tile = 0; tile < 4; ++tile) mx[tile] = fmaxf(mx[tile], __shfl_xor(mx[tile], 16));
#pragma unroll
    for (int tile = 0; tile < 4; ++tile) mx[tile] = fmaxf(mx[tile], __shfl_xor(mx[tile], 32));
    float se[4];
#pragma unroll
    for (int tile = 0; tile < 4; ++tile) {
#pragma unroll
      for (int r = 0; r < 4; ++r) lg[tile][r] = __expf(lg[tile][r] - mx[tile]);
      se[tile] = lg[tile][0] + lg[tile][1] + lg[tile][2] + lg[tile][3];
    }
#pragma unroll
    for (int tile = 0; tile < 4; ++tile) se[tile] += __shfl_xor(se[tile], 16);
#pragma unroll
    for (int tile = 0; tile < 4; ++tile) se[tile] += __shfl_xor(se[tile], 32);
#pragma unroll
    for (int tile = 0; tile < 4; ++tile) {
      const float inv = 1.f / se[tile];
#pragma unroll
      for (int r = 0; r < 4; ++r) {
        const float a = lg[tile][r] * inv + ATTN_EPS;
        sacc[r] += a;
        P[gr][4 * g + r][tile * 16 + t] = (__bf16)a;
        if constexpr (LAST) {
          if (4 * g + r < KSL)
            __builtin_nontemporal_store(
                a, &attn_out[((size_t)b * NTOK + sp * 128 + tb + tile * 16 + t) * KSL + 4 * g + r]);
        }
      }
    }
#pragma unroll
    for (int ks = 0; ks < 2; ++ks) {
      const bf16x8 pf = *(const bf16x8*)&P[gr][t][ks * 32 + g * 8];
#pragma unroll
      for (int ct = 0; ct < 4; ++ct)
        U[ct] = __builtin_amdgcn_mfma_f32_16x16x32_bf16(pf, vf[ks][ct], U[ct], 0, 0, 0);
    }
  }

  float* __restrict__ up = Upart + (size_t)(b * NSPLIT + sp) * (KSL * DSL);
#pragma unroll
  for (int ct = 0; ct < 4; ++ct)
#pragma unroll
    for (int r = 0; r < 4; ++r)
      if (4 * g + r < KSL) up[(4 * g + r) * DSL + ct * 16 + t] = U[ct][r];

#pragma unroll
  for (int r = 0; r < 4; ++r) {
#pragma unroll
    for (int o = 1; o < 16; o <<= 1) sacc[r] += __shfl_xor(sacc[r], o);
  }
  if (t == 0) {
    float* __restrict__ spp = Spart + (size_t)(b * NSPLIT + sp) * 16;
#pragma unroll
    for (int r = 0; r < 4; ++r) spp[4 * g + r] = sacc[r];
  }
}

// ---------------------------------------------------------------------------
// Kernel 4: reduce -> GRU -> LN_f + MLP residual -> next q. 2 waves/row.
// Upart/Spart via nt loads (dead after read). LAST: skip q, nt out store.
// ---------------------------------------------------------------------------
template <bool LAST>
__launch_bounds__(128)
__global__ void k_update(const float* __restrict__ Upart, const float* __restrict__ Spart,
                         float* __restrict__ slots, const float* __restrict__ w_ih,
                         const float* __restrict__ w_hh, const float* __restrict__ b_ih,
                         const float* __restrict__ b_hh, const float* __restrict__ fg,
                         const float* __restrict__ fb, const float* __restrict__ W1,
                         const float* __restrict__ b1v, const float* __restrict__ W2,
                         const float* __restrict__ b2v, const float* __restrict__ qg,
                         const float* __restrict__ qbv, const float* __restrict__ Wq,
                         float* __restrict__ q, float* __restrict__ out_slots) {
  __shared__ float rU[2][64];
  __shared__ float rS[2];
  __shared__ float rG[2][6][64];
  __shared__ float rH[2][4][64];
  __shared__ float rO[2][64];
  __shared__ float rQ[2][64];
  const int w = threadIdx.x >> 6, c = threadIdx.x & 63;
  const int row = blockIdx.x;            // 0..703
  const int b = row / 11, k = row - b * 11;

  float upi = 0.f, ssp = 0.f;
  for (int s = w * 16; s < w * 16 + 16; ++s) {
    upi += __builtin_nontemporal_load(&Upart[((size_t)(b * NSPLIT + s) * KSL + k) * DSL + c]);
    ssp += __builtin_nontemporal_load(&Spart[(size_t)(b * NSPLIT + s) * 16 + k]);
  }
  rU[w][c] = upi;
  if (c == 0) rS[w] = ssp;
  const float h = slots[(size_t)row * DSL + c];
  __syncthreads();
  const float u = (rU[0][c] + rU[1][c]) / (rS[0] + rS[1]);

  float gr = 0.f, gz = 0.f, gn = 0.f, hr = 0.f, hz = 0.f, hn = 0.f;
  for (int i = w * 32; i < w * 32 + 32; ++i) {
    const float ui = __shfl(u, i), hi = __shfl(h, i);
    gr += ui * w_ih[i * 192 + c];       hr += hi * w_hh[i * 192 + c];
    gz += ui * w_ih[i * 192 + 64 + c];  hz += hi * w_hh[i * 192 + 64 + c];
    gn += ui * w_ih[i * 192 + 128 + c]; hn += hi * w_hh[i * 192 + 128 + c];
  }
  rG[w][0][c] = gr; rG[w][1][c] = gz; rG[w][2][c] = gn;
  rG[w][3][c] = hr; rG[w][4][c] = hz; rG[w][5][c] = hn;
  __syncthreads();
  gr = rG[0][0][c] + rG[1][0][c] + b_ih[c];
  gz = rG[0][1][c] + rG[1][1][c] + b_ih[64 + c];
  gn = rG[0][2][c] + rG[1][2][c] + b_ih[128 + c];
  hr = rG[0][3][c] + rG[1][3][c] + b_hh[c];
  hz = rG[0][4][c] + rG[1][4][c] + b_hh[64 + c];
  hn = rG[0][5][c] + rG[1][5][c] + b_hh[128 + c];
  const float r = 1.f / (1.f + __expf(-(gr + hr)));
  const float z = 1.f / (1.f + __expf(-(gz + hz)));
  const float nn = tanhf(gn + r * hn);
  float sv = (1.f - z) * nn + z * h;

  float sum = sv, sq = sv * sv;
#pragma unroll
  for (int o = 32; o > 0; o >>= 1) { sum += __shfl_xor(sum, o); sq += __shfl_xor(sq, o); }
  float m = sum * (1.f / 64.f);
  float rstd = rsqrtf(sq * (1.f / 64.f) - m * m + LN_EPS);
  const float sl = (sv - m) * rstd * fg[c] + fb[c];

  float h0 = 0.f, h1 = 0.f, h2 = 0.f, h3 = 0.f;
  for (int i = w * 32; i < w * 32 + 32; ++i) {
    const float si = __shfl(sl, i);
    h0 += si * W1[i * 256 + c];        h1 += si * W1[i * 256 + 64 + c];
    h2 += si * W1[i * 256 + 128 + c];  h3 += si * W1[i * 256 + 192 + c];
  }
  rH[w][0][c] = h0; rH[w][1][c] = h1; rH[w][2][c] = h2; rH[w][3][c] = h3;
  __syncthreads();
  h0 = fmaxf(rH[0][0][c] + rH[1][0][c] + b1v[c], 0.f);
  h1 = fmaxf(rH[0][1][c] + rH[1][1][c] + b1v[64 + c], 0.f);
  h2 = fmaxf(rH[0][2][c] + rH[1][2][c] + b1v[128 + c], 0.f);
  h3 = fmaxf(rH[0][3][c] + rH[1][3][c] + b1v[192 + c], 0.f);

  float o = 0.f;
  {
    const float ha = (w == 0) ? h0 : h2;
    const float hb = (w == 0) ? h1 : h3;
    const int base = w * 128;
    for (int j = 0; j < 64; ++j) o += __shfl(ha, j) * W2[(base + j) * DSL + c];
    for (int j = 0; j < 64; ++j) o += __shfl(hb, j) * W2[(base + 64 + j) * DSL + c];
  }
  rO[w][c] = o;
  __syncthreads();
  sv += rO[0][c] + rO[1][c] + b2v[c];

  if constexpr (LAST) {
    if (w == 0)
      __builtin_nontemporal_store(sv, &out_slots[(size_t)row * DSL + c]);
  } else {
    float s2 = sv, q2 = sv * sv;
#pragma unroll
    for (int o2 = 32; o2 > 0; o2 >>= 1) { s2 += __shfl_xor(s2, o2); q2 += __shfl_xor(q2, o2); }
    m = s2 * (1.f / 64.f);
    rstd = rsqrtf(q2 * (1.f / 64.f) - m * m + LN_EPS);
    const float qn = (sv - m) * rstd * qg[c] + qbv[c];
    float qa = 0.f;
    for (int i = w * 32; i < w * 32 + 32; ++i) qa += __shfl(qn, i) * Wq[i * DSL + c];
    rQ[w][c] = qa;
    __syncthreads();
    if (w == 0) {
      slots[(size_t)row * DSL + c] = sv;
      q[(size_t)row * DSL + c] = (rQ[0][c] + rQ[1][c]) * SCALE;
    }
  }
}

// ---------------------------------------------------------------------------
extern "C" void kernel_launch(void* const* d_in, const int* in_sizes, int n_in,
                              void* d_out, int out_size, void* d_ws, size_t ws_size,
                              hipStream_t stream) {
  const float* inp  = (const float*)d_in[0];
  const float* lng  = (const float*)d_in[1];
  const float* lnb  = (const float*)d_in[2];
  const float* Wk   = (const float*)d_in[3];
  const float* Wv   = (const float*)d_in[4];
  const float* init = (const float*)d_in[5];
  const float* qg   = (const float*)d_in[6];
  const float* qbb  = (const float*)d_in[7];
  const float* Wq   = (const float*)d_in[8];
  const float* wih  = (const float*)d_in[9];
  const float* whh  = (const float*)d_in[10];
  const float* bih  = (const float*)d_in[11];
  const float* bhh  = (const float*)d_in[12];
  const float* fg   = (const float*)d_in[13];
  const float* fb   = (const float*)d_in[14];
  const float* W1   = (const float*)d_in[15];
  const float* b1   = (const float*)d_in[16];
  const float* W2   = (const float*)d_in[17];
  const float* b2   = (const float*)d_in[18];

  char* wsb = (char*)d_ws;
  __bf16* keys  = (__bf16*)wsb;                                  // 33.55 MB
  __bf16* valsT = keys + (size_t)NB * NTOK * DSL;                // 33.55 MB
  __bf16* WTf   = valsT + (size_t)NB * DSL * NTOK;               // 32 KB
  float*  EP    = (float*)(WTf + 16384);                         // 1 KB
  float* slots = EP + 256;
  float* q     = slots + NB * KSL * DSL;
  float* Upart = q + NB * KSL * DSL;                             // 5.77 MB
  float* Spart = Upart + (size_t)NB * NSPLIT * KSL * DSL;        // 128 KB

  float* out_slots = (float*)d_out;
  float* out_attn  = (float*)d_out + NB * KSL * DSL;

  k_prepinit<<<73, 704, 0, stream>>>(Wk, Wv, lng, lnb, WTf, EP,
                                     init, qg, qbb, Wq, slots, q);
  k_lnproj<<<4096, 256, 0, stream>>>(inp, WTf, EP, keys, valsT);
  for (int t = 0; t < 3; ++t) {
    if (t < 2) {
      k_attn<false><<<NB * NSPLIT, 64, 0, stream>>>(keys, valsT, q, Upart, Spart, nullptr);
      k_update<false><<<NB * KSL, 128, 0, stream>>>(Upart, Spart, slots, wih, whh, bih, bhh,
                                                    fg, fb, W1, b1, W2, b2, qg, qbb, Wq, q,
                                                    nullptr);
    } else {
      k_attn<true><<<NB * NSPLIT, 64, 0, stream>>>(keys, valsT, q, Upart, Spart, out_attn);
      k_update<true><<<NB * KSL, 128, 0, stream>>>(Upart, Spart, slots, wih, whh, bih, bhh,
                                                   fg, fb, W1, b1, W2, b2, qg, qbb, Wq, q,
                                                   out_slots);
    }
  }
}